// Round 2
// baseline (118.730 us; speedup 1.0000x reference)
//
#include <hip/hip_runtime.h>
#include <math.h>

#define N_PRED 12
#define B      256
#define N_NEG  128
#define D      512
#define LOG2E  1.4426950408889634f
#define LN2    0.6931471805599453f

__device__ __forceinline__ float ex2(float x) { return __builtin_amdgcn_exp2f(x); }

// One block per (t,b). 4 waves. Each wave processes 4 negs per iteration,
// 16 lanes per neg (lane q = lane&15 owns d-slice [q*32, q*32+32)).
__global__ __launch_bounds__(256) void fk_kernel(
    const float* __restrict__ lp,        // (13,256,512)
    const float* __restrict__ ps,        // (12,256,512)
    const int*   __restrict__ time_idx,  // (12,256,128)
    const int*   __restrict__ batch_idx, // (12,256,128)
    float* __restrict__ per_step,        // (12*256)
    float* __restrict__ flags)           // (12*256)
{
    const int tb   = blockIdx.x;   // 0..3071
    const int t    = tb >> 8;
    const int b    = tb & (B - 1);
    const int tid  = threadIdx.x;
    const int wave = tid >> 6;
    const int lane = tid & 63;
    const int q    = lane & 15;    // sub-lane within neg-group
    const int g    = lane >> 4;    // neg-group id (0..3)

    __shared__ int   s_ti[N_NEG];
    __shared__ int   s_bi[N_NEG];
    __shared__ float s_sum[4];
    __shared__ int   s_ok[4];

    // Stage this block's 128 (ti,bi) index pairs into LDS (one pass, no
    // per-iteration global index latency).
    const int idx_base = (t * B + b) * N_NEG;
    if (tid < N_NEG) s_ti[tid]         = time_idx[idx_base + tid];
    else             s_bi[tid - N_NEG] = batch_idx[idx_base + tid - N_NEG];

    // pred slice for this lane, pre-scaled by log2(e): exp(p*x) = exp2(pl*x)
    const float4* pred4 = (const float4*)(lp + ((size_t)(t + 1) * B + b) * D) + q * 8;
    float4 p[8];
#pragma unroll
    for (int j = 0; j < 8; ++j) {
        float4 v = pred4[j];
        v.x *= LOG2E; v.y *= LOG2E; v.z *= LOG2E; v.w *= LOG2E;
        p[j] = v;
    }

    // fk_pos (all 4 groups compute the identical value concurrently)
    const float4* pos4 = (const float4*)(ps + ((size_t)t * B + b) * D) + q * 8;
    float a0 = 0.f, a1 = 0.f, a2 = 0.f, a3 = 0.f;
#pragma unroll
    for (int j = 0; j < 8; ++j) {
        float4 y = pos4[j];
        a0 += ex2(p[j].x * y.x);
        a1 += ex2(p[j].y * y.y);
        a2 += ex2(p[j].z * y.z);
        a3 += ex2(p[j].w * y.w);
    }
    float s = (a0 + a1) + (a2 + a3);
#pragma unroll
    for (int off = 1; off < 16; off <<= 1) s += __shfl_xor(s, off, 64);
    const float fk_pos = s;   // uniform across the wave

    __syncthreads();          // indices staged

    float negsum = 0.0f;
    bool  all_ok = true;

#pragma unroll 2
    for (int it = 0; it < 8; ++it) {
        const int n  = wave * 32 + it * 4 + g;
        const int ti = s_ti[n];
        const int bi = s_bi[n];
        // bank[ti, bi, :] : ti==0 -> lp[0, bi], else ps[ti-1, bi]
        const float* row = (ti == 0) ? (lp + (size_t)bi * D)
                                     : (ps + ((size_t)(ti - 1) * B + bi) * D);
        const float4* row4 = (const float4*)row + q * 8;
        float b0 = 0.f, b1 = 0.f, b2 = 0.f, b3 = 0.f;
#pragma unroll
        for (int j = 0; j < 8; ++j) {
            float4 y = row4[j];
            b0 += ex2(p[j].x * y.x);
            b1 += ex2(p[j].y * y.y);
            b2 += ex2(p[j].z * y.z);
            b3 += ex2(p[j].w * y.w);
        }
        float fk = (b0 + b1) + (b2 + b3);
        // 4-step reduce within each 16-lane group (all 4 groups concurrently)
#pragma unroll
        for (int off = 1; off < 16; off <<= 1) fk += __shfl_xor(fk, off, 64);
        negsum += fk;                  // identical in all 16 lanes of a group
        all_ok  = all_ok && (fk_pos > fk);
    }

    const int wave_ok = __all(all_ok ? 1 : 0);
    // Cross-group combine only (offsets 16,32): exact wave total, 2 shuffles.
    float ns = negsum;
#pragma unroll
    for (int off = 16; off < 64; off <<= 1) ns += __shfl_xor(ns, off, 64);

    if (lane == 0) { s_sum[wave] = ns; s_ok[wave] = wave_ok; }
    __syncthreads();
    if (tid == 0) {
        float total_neg = (s_sum[0] + s_sum[1]) + (s_sum[2] + s_sum[3]);
        int   ok        = s_ok[0] & s_ok[1] & s_ok[2] & s_ok[3];
        float total     = fk_pos + total_neg;
        float lg = (__builtin_amdgcn_logf(fk_pos) - __builtin_amdgcn_logf(total)) * LN2;
        per_step[tb] = lg;
        flags[tb]    = (float)ok;
    }
}

// Block 0: loss; blocks 1..12: correct_predictions[t]
__global__ __launch_bounds__(256) void reduce_kernel(
    const float* __restrict__ per_step,
    const float* __restrict__ flags,
    float* __restrict__ out)
{
    const int tid = threadIdx.x;
    const int j   = blockIdx.x;
    __shared__ float sh[4];

    float s = 0.0f;
    if (j == 0) {
#pragma unroll
        for (int t = 0; t < N_PRED; ++t) s += per_step[t * B + tid];
    } else {
        s = flags[(j - 1) * B + tid];
    }
#pragma unroll
    for (int off = 32; off > 0; off >>= 1) s += __shfl_xor(s, off, 64);
    if ((tid & 63) == 0) sh[tid >> 6] = s;
    __syncthreads();
    if (tid == 0) {
        float tot = (sh[0] + sh[1]) + (sh[2] + sh[3]);
        if (j == 0)
            out[0] = tot * (1.0f / ((float)(N_NEG + 1) * N_PRED * B));
        else
            out[j] = tot;
    }
}

extern "C" void kernel_launch(void* const* d_in, const int* in_sizes, int n_in,
                              void* d_out, int out_size, void* d_ws, size_t ws_size,
                              hipStream_t stream) {
    const float* lp        = (const float*)d_in[0];
    const float* ps        = (const float*)d_in[1];
    const int*   time_idx  = (const int*)d_in[2];
    const int*   batch_idx = (const int*)d_in[3];
    float* out = (float*)d_out;

    float* per_step = (float*)d_ws;
    float* flags    = per_step + N_PRED * B;

    fk_kernel<<<N_PRED * B, 256, 0, stream>>>(lp, ps, time_idx, batch_idx,
                                              per_step, flags);
    reduce_kernel<<<1 + N_PRED, 256, 0, stream>>>(per_step, flags, out);
}

// Round 3
// 56.513 us; speedup vs baseline: 2.1009x; 2.1009x over previous
//
#include <hip/hip_runtime.h>
#include <math.h>

#define N_PRED 12
#define B      256
#define N_NEG  128
#define D      512
#define LOG2E  1.4426950408889634f
#define LN2    0.6931471805599453f

__device__ __forceinline__ float ex2(float x) { return __builtin_amdgcn_exp2f(x); }

// One block per (t,b). 4 waves. Each wave processes 4 negs per iteration,
// 16 lanes per neg. CYCLIC d-mapping: lane q owns float4 indices q+16j
// (j=0..7), so each load instruction is a contiguous 256B segment per group
// (1 KB per wave instruction) — full coalescing, unlike the R2 block mapping.
__global__ __launch_bounds__(256) void fk_kernel(
    const float* __restrict__ lp,        // (13,256,512)
    const float* __restrict__ ps,        // (12,256,512)
    const int*   __restrict__ time_idx,  // (12,256,128)
    const int*   __restrict__ batch_idx, // (12,256,128)
    float* __restrict__ per_step,        // (12*256)
    float* __restrict__ flags)           // (12*256)
{
    const int tb   = blockIdx.x;   // 0..3071
    const int t    = tb >> 8;
    const int b    = tb & (B - 1);
    const int tid  = threadIdx.x;
    const int wave = tid >> 6;
    const int lane = tid & 63;
    const int q    = lane & 15;    // sub-lane within neg-group
    const int g    = lane >> 4;    // neg-group id (0..3)

    __shared__ int   s_ti[N_NEG];
    __shared__ int   s_bi[N_NEG];
    __shared__ float s_sum[4];
    __shared__ int   s_ok[4];

    // Stage this block's 128 (ti,bi) index pairs into LDS once.
    const int idx_base = (t * B + b) * N_NEG;
    if (tid < N_NEG) s_ti[tid]         = time_idx[idx_base + tid];
    else             s_bi[tid - N_NEG] = batch_idx[idx_base + tid - N_NEG];

    // pred slice for this lane (cyclic), pre-scaled by log2(e).
    const float4* pred4 = (const float4*)(lp + ((size_t)(t + 1) * B + b) * D) + q;
    float4 p[8];
#pragma unroll
    for (int j = 0; j < 8; ++j) {
        float4 v = pred4[j * 16];
        v.x *= LOG2E; v.y *= LOG2E; v.z *= LOG2E; v.w *= LOG2E;
        p[j] = v;
    }

    // fk_pos (all 4 groups compute the identical value concurrently)
    const float4* pos4 = (const float4*)(ps + ((size_t)t * B + b) * D) + q;
    float a0 = 0.f, a1 = 0.f, a2 = 0.f, a3 = 0.f;
#pragma unroll
    for (int j = 0; j < 8; ++j) {
        float4 y = pos4[j * 16];
        a0 += ex2(p[j].x * y.x);
        a1 += ex2(p[j].y * y.y);
        a2 += ex2(p[j].z * y.z);
        a3 += ex2(p[j].w * y.w);
    }
    float s = (a0 + a1) + (a2 + a3);
#pragma unroll
    for (int off = 1; off < 16; off <<= 1) s += __shfl_xor(s, off, 64);
    const float fk_pos = s;   // uniform across the wave

    __syncthreads();          // indices staged

    float negsum = 0.0f;
    bool  all_ok = true;

#pragma unroll 2
    for (int it = 0; it < 8; ++it) {
        const int n  = wave * 32 + it * 4 + g;
        const int ti = s_ti[n];
        const int bi = s_bi[n];
        // bank[ti, bi, :] : ti==0 -> lp[0, bi], else ps[ti-1, bi]
        const float* row = (ti == 0) ? (lp + (size_t)bi * D)
                                     : (ps + ((size_t)(ti - 1) * B + bi) * D);
        const float4* row4 = (const float4*)row + q;
        float b0 = 0.f, b1 = 0.f, b2 = 0.f, b3 = 0.f;
#pragma unroll
        for (int j = 0; j < 8; ++j) {
            float4 y = row4[j * 16];
            b0 += ex2(p[j].x * y.x);
            b1 += ex2(p[j].y * y.y);
            b2 += ex2(p[j].z * y.z);
            b3 += ex2(p[j].w * y.w);
        }
        float fk = (b0 + b1) + (b2 + b3);
        // 4-step reduce within each 16-lane group (all 4 groups concurrently)
#pragma unroll
        for (int off = 1; off < 16; off <<= 1) fk += __shfl_xor(fk, off, 64);
        negsum += fk;                  // identical in all 16 lanes of a group
        all_ok  = all_ok && (fk_pos > fk);
    }

    const int wave_ok = __all(all_ok ? 1 : 0);
    // Cross-group combine only (offsets 16,32): exact wave total, 2 shuffles.
    float ns = negsum;
#pragma unroll
    for (int off = 16; off < 64; off <<= 1) ns += __shfl_xor(ns, off, 64);

    if (lane == 0) { s_sum[wave] = ns; s_ok[wave] = wave_ok; }
    __syncthreads();
    if (tid == 0) {
        float total_neg = (s_sum[0] + s_sum[1]) + (s_sum[2] + s_sum[3]);
        int   ok        = s_ok[0] & s_ok[1] & s_ok[2] & s_ok[3];
        float total     = fk_pos + total_neg;
        float lg = (__builtin_amdgcn_logf(fk_pos) - __builtin_amdgcn_logf(total)) * LN2;
        per_step[tb] = lg;
        flags[tb]    = (float)ok;
    }
}

// Block 0: loss; blocks 1..12: correct_predictions[t]
__global__ __launch_bounds__(256) void reduce_kernel(
    const float* __restrict__ per_step,
    const float* __restrict__ flags,
    float* __restrict__ out)
{
    const int tid = threadIdx.x;
    const int j   = blockIdx.x;
    __shared__ float sh[4];

    float s = 0.0f;
    if (j == 0) {
#pragma unroll
        for (int t = 0; t < N_PRED; ++t) s += per_step[t * B + tid];
    } else {
        s = flags[(j - 1) * B + tid];
    }
#pragma unroll
    for (int off = 32; off > 0; off >>= 1) s += __shfl_xor(s, off, 64);
    if ((tid & 63) == 0) sh[tid >> 6] = s;
    __syncthreads();
    if (tid == 0) {
        float tot = (sh[0] + sh[1]) + (sh[2] + sh[3]);
        if (j == 0)
            out[0] = tot * (1.0f / ((float)(N_NEG + 1) * N_PRED * B));
        else
            out[j] = tot;
    }
}

extern "C" void kernel_launch(void* const* d_in, const int* in_sizes, int n_in,
                              void* d_out, int out_size, void* d_ws, size_t ws_size,
                              hipStream_t stream) {
    const float* lp        = (const float*)d_in[0];
    const float* ps        = (const float*)d_in[1];
    const int*   time_idx  = (const int*)d_in[2];
    const int*   batch_idx = (const int*)d_in[3];
    float* out = (float*)d_out;

    float* per_step = (float*)d_ws;
    float* flags    = per_step + N_PRED * B;

    fk_kernel<<<N_PRED * B, 256, 0, stream>>>(lp, ps, time_idx, batch_idx,
                                              per_step, flags);
    reduce_kernel<<<1 + N_PRED, 256, 0, stream>>>(per_step, flags, out);
}